// Round 9
// baseline (274.562 us; speedup 1.0000x reference)
//
#include <hip/hip_runtime.h>

// multi_SelfAttention on MI355X (gfx950). Inputs fp32 (runtime-detected);
// bf16 MFMA compute; output dtype per flag.
// r16: (a) attn: l-sum moved off the VALU pipe -- a ones-row A-fragment MFMA
// (row0=1, else 0) accumulates sum_j P[j][q] into lsum C[0][q] alongside PV
// (4 extra MFMA/iter on the 30%-busy pipe, ~37 fewer VALU insts on the
// 62%-busy pipe). (b) proj1+proj2 fused into gemm_qkv: phase1 = gemm64
// structure -> zb[64,64] in LDS (no global round trip), phase2 = 8 N-chunks
// of zb @ fc*_w^T with DMA staging; kills one launch + 6MB traffic. Grid 384
// (r14 grid-starvation lesson: never below ~1.5 blocks/CU).
// Launches: detect -> mega_convert -> gemm_qkv -> attn -> gemm128(proj3).

typedef __bf16 bf16x8 __attribute__((ext_vector_type(8)));
typedef __bf16 bf16x4 __attribute__((ext_vector_type(4)));
typedef __bf16 bf16x2 __attribute__((ext_vector_type(2)));
typedef float floatx4 __attribute__((ext_vector_type(4)));
typedef float floatx16 __attribute__((ext_vector_type(16)));
typedef unsigned int uintx4 __attribute__((ext_vector_type(4)));
typedef unsigned int uintx2 __attribute__((ext_vector_type(2)));

// 64-stride tile swizzle: 16B-chunk XOR; bank-uniform for row-major b128
// reads at fixed col, b128 row-staging writes, and b32 transpose stores.
#define SW64(row, col) (((row) << 6) | (((((col) >> 3) ^ ((row) & 7) ^ (((row) >> 3) & 7)) << 3) | ((col) & 7)))

#if __has_builtin(__builtin_amdgcn_exp2f)
__device__ __forceinline__ float fast_exp2(float x) { return __builtin_amdgcn_exp2f(x); }
#else
__device__ __forceinline__ float fast_exp2(float x) { return exp2f(x); }
#endif

__device__ __forceinline__ unsigned int pack_bf16(float lo, float hi) {
    bf16x2 w; w[0] = (__bf16)lo; w[1] = (__bf16)hi;
    return __builtin_bit_cast(unsigned int, w);
}
__device__ __forceinline__ unsigned int pack2(__bf16 lo, __bf16 hi) {
    bf16x2 w; w[0] = lo; w[1] = hi;
    return __builtin_bit_cast(unsigned int, w);
}
// Cross-half exchange (lanes 0-31 <-> 32-63), verified builtin w/ shfl fallback.
#if __has_builtin(__builtin_amdgcn_permlane32_swap)
__device__ __forceinline__ void xchg(unsigned int& X, unsigned int& Y, int) {
    uintx2 r = __builtin_amdgcn_permlane32_swap(X, Y, false, false);
    X = r[0]; Y = r[1];
}
#else
__device__ __forceinline__ void xchg(unsigned int& X, unsigned int& Y, int hl) {
    unsigned int sX = (unsigned int)__shfl_xor((int)X, 32);
    unsigned int sY = (unsigned int)__shfl_xor((int)Y, 32);
    unsigned int lo = hl ? sY : X;
    unsigned int hi = hl ? Y : sX;
    X = lo; Y = hi;
}
#endif
__device__ __forceinline__ bf16x8 frag4(unsigned int a, unsigned int b, unsigned int c, unsigned int d) {
    uintx4 u; u[0] = a; u[1] = b; u[2] = c; u[3] = d;
    return __builtin_bit_cast(bf16x8, u);
}
// Async global->LDS DMA, 16 B/lane. LDS base must be wave-uniform; HW writes
// base + lane*16. Global addr is per-lane (pre-swizzle it for swizzled layouts).
__device__ __forceinline__ void async_b128(const __bf16* g, __bf16* l) {
    __builtin_amdgcn_global_load_lds(
        (const __attribute__((address_space(1))) unsigned int*)g,
        (__attribute__((address_space(3))) unsigned int*)l, 16, 0, 0);
}

__device__ __forceinline__ bf16x8 cvt8(const void* src, int f, long idx) {
    bf16x8 v;
    if (f) {
        const float* s = (const float*)src + idx;
        float4 f0 = *(const float4*)s;
        float4 f1 = *(const float4*)(s + 4);
        v[0] = (__bf16)f0.x; v[1] = (__bf16)f0.y; v[2] = (__bf16)f0.z; v[3] = (__bf16)f0.w;
        v[4] = (__bf16)f1.x; v[5] = (__bf16)f1.y; v[6] = (__bf16)f1.z; v[7] = (__bf16)f1.w;
    } else {
        v = *(const bf16x8*)((const __bf16*)src + idx);
    }
    return v;
}

// ---------------------------------------------------------------------------
__global__ void detect_dtype(const unsigned short* __restrict__ z, int* __restrict__ flag) {
    __shared__ int cnt;
    if (threadIdx.x == 0) cnt = 0;
    __syncthreads();
    int local = 0;
    for (int i = threadIdx.x; i < 16384; i += 256) {
        unsigned int u = (unsigned int)z[i] << 16;
        float x = __uint_as_float(u);
        float ax = fabsf(x);
        if (!(ax <= 1024.0f) || (x != 0.0f && ax < 1e-20f)) local++;
    }
    atomicAdd(&cnt, local);
    __syncthreads();
    if (threadIdx.x == 0) *flag = (cnt > 1310) ? 1 : 0;
}

// ---------------------------------------------------------------------------
// mega_convert: one kernel for the whole input-prep stage.
//   blocks [0,1024):   z [8192,1024] convert/copy -> cv+0 (32 elems/thread)
//   blocks [1024,1026): 4 biases (consecutive dst at cv+9830400)
//   blocks [1026,1378): 64x64 transpose-convert tiles for 7 weight matrices:
//     t<48:  wq/wk/wv [1024,64] -> ^T [64,1024]   at cv+8388608 + m*65536
//     t<96:  fc*_w    [64,1024] -> ^T [1024,64]   at cv+8585216 + m*65536
//     else:  fco_w  [1024,1024] -> ^T [1024,1024] at cv+8781824
// ---------------------------------------------------------------------------
struct MegaArgs { const void* z; const void* bias[4]; const void* w[7]; };

__global__ __launch_bounds__(256) void mega_convert(MegaArgs a, __bf16* __restrict__ cv,
                                                    const int* __restrict__ flag) {
    const int f = *flag;
    const unsigned int blk = blockIdx.x;
    const int tid = threadIdx.x;

    if (blk < 1024) {           // z: 8388608 elems, 8192/block
        const long base = (long)blk * 8192 + tid * 8;
        #pragma unroll
        for (int p = 0; p < 4; p++) {
            const long i = base + p * 2048;
            *(bf16x8*)&cv[i] = cvt8(a.z, f, i);
        }
        return;
    }
    if (blk < 1026) {           // biases: 4 x 1024, consecutive dst
        const int idx = (((int)blk - 1024) * 256 + tid) * 8;
        const int b = idx >> 10, o = idx & 1023;
        *(bf16x8*)&cv[9830400 + b * 1024 + o] = cvt8(a.bias[b], f, o);
        return;
    }
    // ---- transpose-convert tiles
    const int t = blk - 1026;
    int bx, by, R, C;
    const void* src;
    __bf16* dst;
    if (t < 48) {
        const int m = t >> 4; by = t & 15; bx = 0; R = 1024; C = 64;
        src = a.w[m]; dst = cv + 8388608 + m * 65536;
    } else if (t < 96) {
        const int m = (t - 48) >> 4; bx = (t - 48) & 15; by = 0; R = 64; C = 1024;
        src = a.w[3 + m]; dst = cv + 8585216 + m * 65536;
    } else {
        const int u = t - 96; bx = u & 15; by = u >> 4; R = 1024; C = 1024;
        src = a.w[6]; dst = cv + 8781824;
    }
    __shared__ __bf16 tl[64][72];
    const int r0 = by * 64, c0 = bx * 64;
    const int rr = tid >> 3, c8 = (tid & 7) << 3;
    #pragma unroll
    for (int p = 0; p < 2; p++) {
        bf16x8 v = cvt8(src, f, (long)(r0 + p * 32 + rr) * C + c0 + c8);
        #pragma unroll
        for (int j = 0; j < 8; j++) tl[c8 + j][p * 32 + rr] = v[j];
    }
    __syncthreads();
    #pragma unroll
    for (int p = 0; p < 2; p++) {
        bf16x8 v;
        #pragma unroll
        for (int j = 0; j < 8; j++) v[j] = tl[p * 32 + rr][c8 + j];
        *(bf16x8*)&dst[(long)(c0 + p * 32 + rr) * R + r0 + c8] = v;
    }
}

// ---------------------------------------------------------------------------
// gemm_qkv (proj1+proj2 fused): per block (64 M-rows, one of q/k/v):
//   phase 1: zb[64,64] = z[64,1024] @ W1T[64,1024]^T   (gemm64 structure)
//   zb -> LDS (bf16, SW64), ONE LDS round trip instead of a global one
//   phase 2: out[64,1024] = (zb @ W2T[1024,64]^T + bias) * os, 8 N-chunks
// Both phases stage via global_load_lds with SW64-pre-swizzled sources.
// ---------------------------------------------------------------------------
__global__ __launch_bounds__(256, 2) void gemm_qkv(
    const __bf16* __restrict__ A,      // z [8192,1024]
    const __bf16* __restrict__ W1T,    // wq/wk/wv^T [64,1024] x3, 65536 stride
    const __bf16* __restrict__ W2T,    // fc*_w^T [1024,64] x3, 65536 stride
    const __bf16* __restrict__ biases, // fcq_b|fck_b|fcv_b consecutive
    __bf16* __restrict__ Q0, __bf16* __restrict__ Q1, __bf16* __restrict__ Q2,
    float os0)
{
    const int zsel = blockIdx.z;
    const __bf16* BT1 = W1T + zsel * 65536;
    const __bf16* BT2 = W2T + zsel * 65536;
    const __bf16* bias = biases + zsel * 1024;
    __bf16* Q = (zsel == 0) ? Q0 : (zsel == 1) ? Q1 : Q2;
    const float oscale = (zsel == 0) ? os0 : 1.0f;

    const int m0 = blockIdx.x * 64;
    const int tid = threadIdx.x;
    const int wave = tid >> 6, ln = tid & 63;
    const int l15 = tid & 15, quad = (tid >> 4) & 3;

    __shared__ __bf16 As[64 * 64];    // ph1 A, 8 KB
    __shared__ __bf16 Bs[64 * 64];    // ph1 B, 8 KB
    __shared__ __bf16 Zs[64 * 64];    // zb bf16, 8 KB
    __shared__ __bf16 Ws[128 * 64];   // ph2 B chunk, 16 KB

    const int r_off = ln >> 3, j_off = ln & 7;
    floatx4 acc[4] = {};

    for (int k0 = 0; k0 < 1024; k0 += 64) {
        __syncthreads();
        #pragma unroll
        for (int it = 0; it < 2; it++) {
            const int seg = wave * 2 + it;
            const int row = seg * 8 + r_off;
            const int c = j_off ^ (row & 7) ^ ((row >> 3) & 7);
            async_b128(&A[(long)(m0 + row) * 1024 + k0 + c * 8], &As[seg * 512]);
            async_b128(&BT1[(long)row * 1024 + k0 + c * 8], &Bs[seg * 512]);
        }
        __syncthreads();
        #pragma unroll
        for (int ks = 0; ks < 2; ks++) {
            bf16x8 av = *(const bf16x8*)&As[SW64(wave * 16 + l15, ks * 32 + quad * 8)];
            #pragma unroll
            for (int nt = 0; nt < 4; nt++) {
                bf16x8 bv = *(const bf16x8*)&Bs[SW64(nt * 16 + l15, ks * 32 + quad * 8)];
                acc[nt] = __builtin_amdgcn_mfma_f32_16x16x32_bf16(av, bv, acc[nt], 0, 0, 0);
            }
        }
    }
    // zb -> Zs (bf16). Write->read ordering covered by the nc=0 top barrier.
    #pragma unroll
    for (int nt = 0; nt < 4; nt++) {
        const int col = nt * 16 + l15;
        #pragma unroll
        for (int r = 0; r < 4; r++)
            Zs[SW64(wave * 16 + quad * 4 + r, col)] = (__bf16)acc[nt][r];
    }
    // phase 2: 8 chunks of 128 output cols
    for (int nc = 0; nc < 8; nc++) {
        __syncthreads();   // prev-chunk Ws reads drained; Zs writes visible (nc=0)
        #pragma unroll
        for (int it = 0; it < 4; it++) {
            const int seg = wave * 4 + it;
            const int row = seg * 8 + r_off;
            const int c = j_off ^ (row & 7) ^ ((row >> 3) & 7);
            async_b128(&BT2[(long)(nc * 128 + row) * 64 + c * 8], &Ws[seg * 512]);
        }
        __syncthreads();   // DMA drained (compiler emits vmcnt(0) before barrier)
        floatx4 acc2[8] = {};
        #pragma unroll
        for (int ks = 0; ks < 2; ks++) {
            bf16x8 av = *(const bf16x8*)&Zs[SW64(wave * 16 + l15, ks * 32 + quad * 8)];
            #pragma unroll
            for (int nt = 0; nt < 8; nt++) {
                bf16x8 bv = *(const bf16x8*)&Ws[SW64(nt * 16 + l15, ks * 32 + quad * 8)];
                acc2[nt] = __builtin_amdgcn_mfma_f32_16x16x32_bf16(av, bv, acc2[nt], 0, 0, 0);
            }
        }
        #pragma unroll
        for (int nt = 0; nt < 8; nt++) {
            const int col = nc * 128 + nt * 16 + l15;
            float bv = (float)bias[col];
            #pragma unroll
            for (int r = 0; r < 4; r++)
                Q[(long)(m0 + wave * 16 + quad * 4 + r) * 1024 + col] =
                    (__bf16)((acc2[nt][r] + bv) * oscale);
        }
    }
}

// ---------------------------------------------------------------------------
// gemm128 (proj3): C[M,N] = (A @ BT^T + bias) * os. 128x128 tile, BK=64,
// 2x2 waves, global_load_lds staging with SW64-pre-swizzled sources.
// ---------------------------------------------------------------------------
__global__ __launch_bounds__(256, 2) void gemm128(
    const __bf16* __restrict__ A, const __bf16* __restrict__ BT,
    const __bf16* __restrict__ bias, void* __restrict__ C,
    int M, int N, int K, const int* flagp, float oscale)
{
    const int out_fp32 = flagp ? *flagp : 0;
    const int m0 = blockIdx.x * 128;
    const int n0 = blockIdx.y * 128;
    const int tid = threadIdx.x;
    const int wave = tid >> 6, ln = tid & 63;
    const int wr = wave >> 1, wc = wave & 1;    // 2x2 wave grid
    const int l15 = tid & 15, quad = (tid >> 4) & 3;

    __shared__ __bf16 As[128 * 64];   // SW64 layout [m][k], 16 KB
    __shared__ __bf16 Bs[128 * 64];   // SW64 layout [n][k], 16 KB

    const int r_off = ln >> 3, j_off = ln & 7;

    floatx4 acc[4][4] = {};

    for (int k0 = 0; k0 < K; k0 += 64) {
        __syncthreads();
        #pragma unroll
        for (int it = 0; it < 4; it++) {
            const int seg = wave * 4 + it;
            const int row = seg * 8 + r_off;
            const int c = j_off ^ (row & 7) ^ ((row >> 3) & 7);
            async_b128(&A[(long)(m0 + row) * K + k0 + c * 8], &As[seg * 512]);
            async_b128(&BT[(long)(n0 + row) * K + k0 + c * 8], &Bs[seg * 512]);
        }
        __syncthreads();
        #pragma unroll
        for (int ks = 0; ks < 2; ks++) {
            bf16x8 a[4], b[4];
            #pragma unroll
            for (int rt = 0; rt < 4; rt++)
                a[rt] = *(const bf16x8*)&As[SW64(wr * 64 + rt * 16 + l15, ks * 32 + quad * 8)];
            #pragma unroll
            for (int nt = 0; nt < 4; nt++)
                b[nt] = *(const bf16x8*)&Bs[SW64(wc * 64 + nt * 16 + l15, ks * 32 + quad * 8)];
            #pragma unroll
            for (int rt = 0; rt < 4; rt++)
                #pragma unroll
                for (int nt = 0; nt < 4; nt++)
                    acc[rt][nt] = __builtin_amdgcn_mfma_f32_16x16x32_bf16(a[rt], b[nt], acc[rt][nt], 0, 0, 0);
        }
    }
    #pragma unroll
    for (int rt = 0; rt < 4; rt++) {
        const int row = m0 + wr * 64 + rt * 16 + quad * 4;
        #pragma unroll
        for (int nt = 0; nt < 4; nt++) {
            const int col = n0 + wc * 64 + nt * 16 + l15;
            float bv = (float)bias[col];
            #pragma unroll
            for (int r = 0; r < 4; r++) {
                float val = (acc[rt][nt][r] + bv) * oscale;
                if (out_fp32) ((float*)C)[(long)(row + r) * N + col] = val;
                else ((__bf16*)C)[(long)(row + r) * N + col] = (__bf16)val;
            }
        }
    }
}

// ---------------------------------------------------------------------------
// Flash attention r16 (32x32 S^T / O^T, in-register P, single-barrier loop).
// l-sum via ones-row MFMA: A-frag = 1.0 at row0 (l31==0), 0 elsewhere;
// lsum = mfma(ones, P-frag, lsum) accumulates sum_j P[j][q] into C[0][q]
// (reg0 @ hl=0). Kills ~37 VALU insts/iter on the 62%-busy VALU pipe for
// 4 MFMA/iter on the 30%-busy matrix pipe.
// ---------------------------------------------------------------------------
__global__ __launch_bounds__(256, 3) void attn_kernel(
    const __bf16* __restrict__ Qg, const __bf16* __restrict__ Kg,
    const __bf16* __restrict__ Vg, __bf16* __restrict__ Og)
{
    const int bh = blockIdx.x;
    const int b = bh >> 4, h = bh & 15;
    const int q0 = blockIdx.y * 128;
    const int base = b * 2048 * 1024 + h * 64;
    const int tid = threadIdx.x;
    const int wave = tid >> 6, ln = tid & 63;
    const int l31 = ln & 31, hl = ln >> 5;    // lane-in-32, lane half
    const int h8 = hl * 8;

    __shared__ __bf16 Ks[2][64 * 64];     // 16 KB, double buffer, SW64 [j][k]
    __shared__ __bf16 VTs[2][64 * 64];    // 16 KB, double buffer, SW64 [d][j]

    // Q fragments (B-operand of S^T): lane n=q=l31, k = ks*16 + h8 + e
    bf16x8 qf[4];
    #pragma unroll
    for (int ks = 0; ks < 4; ks++)
        qf[ks] = *(const bf16x8*)&Qg[base + (q0 + wave * 32 + l31) * 1024 + ks * 16 + h8];

    // ones-row A-fragment for the l-sum MFMA: A[row][k] = (row==0) ? 1 : 0.
    // A-operand layout (established by Ks usage): row = l31, k per-lane.
    bf16x8 onesf;
    {
        __bf16 v = (l31 == 0) ? (__bf16)1.0f : (__bf16)0.0f;
        #pragma unroll
        for (int e = 0; e < 8; e++) onesf[e] = v;
    }

    const int kr = tid >> 3, kc = (tid & 7) << 3;   // K staging: rows kr, kr+32
    const int vr2 = (tid >> 3) * 2, vc = (tid & 7) << 3;  // V staging: row pair

    {   // tile 0 (published by the t=0 barrier)
        bf16x8 ka = *(const bf16x8*)&Kg[base + kr * 1024 + kc];
        bf16x8 kb = *(const bf16x8*)&Kg[base + (kr + 32) * 1024 + kc];
        bf16x8 va = *(const bf16x8*)&Vg[base + vr2 * 1024 + vc];
        bf16x8 vb = *(const bf16x8*)&Vg[base + (vr2 + 1) * 1024 + vc];
        *(bf16x8*)&Ks[0][SW64(kr, kc)] = ka;
        *(bf16x8*)&Ks[0][SW64(kr + 32, kc)] = kb;
        #pragma unroll
        for (int j = 0; j < 8; j++)
            *(unsigned int*)&VTs[0][SW64(vc + j, vr2)] = pack2(va[j], vb[j]);
    }

    floatx16 o_acc[2] = {};
    floatx16 lsum = {};
    float m_i = -1e30f;

    for (int t = 0; t < 32; t++) {
        const int cur = t & 1, nxt = cur ^ 1;
        bf16x8 nka, nkb, nva, nvb;          // K/V(t+1) register prefetch
        if (t < 31) {
            const int kvn = (t + 1) * 64;
            nka = *(const bf16x8*)&Kg[base + (kvn + kr) * 1024 + kc];
            nkb = *(const bf16x8*)&Kg[base + (kvn + kr + 32) * 1024 + kc];
            nva = *(const bf16x8*)&Vg[base + (kvn + vr2) * 1024 + vc];
            nvb = *(const bf16x8*)&Vg[base + (kvn + vr2 + 1) * 1024 + vc];
        }
        __syncthreads();  // writes(t-1) -> nxt_{t-1}=cur visible; reads(t-1) drained

        // ---- S^T = K · Q^T: lane q=l31; j = (r&3)+8*(r>>2)+4*hl (+32 for s1)
        floatx16 sv[2] = {};
        #pragma unroll
        for (int ks = 0; ks < 4; ks++) {
            bf16x8 a0 = *(const bf16x8*)&Ks[cur][SW64(l31, ks * 16 + h8)];
            bf16x8 a1 = *(const bf16x8*)&Ks[cur][SW64(32 + l31, ks * 16 + h8)];
            sv[0] = __builtin_amdgcn_mfma_f32_32x32x16_bf16(a0, qf[ks], sv[0], 0, 0, 0);
            sv[1] = __builtin_amdgcn_mfma_f32_32x32x16_bf16(a1, qf[ks], sv[1], 0, 0, 0);
        }

        // ---- softmax max for q=l31 over 64 j (left-nested for v_max3 fusion)
        float m8[8];
        #pragma unroll
        for (int r = 0; r < 8; r++)
            m8[r] = fmaxf(fmaxf(fmaxf(sv[0][r], sv[0][r + 8]), sv[1][r]), sv[1][r + 8]);
        float ma = fmaxf(fmaxf(m8[0], m8[1]), m8[2]);
        float mb = fmaxf(fmaxf(m8[3], m8[4]), m8[5]);
        float mc = fmaxf(fmaxf(m8[6], m8[7]), ma);
        float mx = fmaxf(mb, mc);
        mx = fmaxf(mx, __shfl_xor(mx, 32));

        if (__any(mx > m_i + 8.0f)) {       // defer-max: rescale only on big jumps
            float m_new = fmaxf(m_i, mx);
            float alpha = fast_exp2(m_i - m_new);
            m_i = m_new;
            lsum[0] *= alpha;               // only reg0 (row 0) carries the sum
            #pragma unroll
            for (int dt = 0; dt < 2; dt++)
                #pragma unroll
                for (int r = 0; r < 16; r++) o_acc[dt][r] *= alpha;
        }

        // ---- P: exp2 -> bf16 pack -> cross-half exchange, fused per 8-group
        // (fp32 values die within the group; row-sum now done by MFMA below)
        bf16x8 pf0, pf1, pf2, pf3;
        #define PGROUP(SVV, BASE, PF) { \
            float e0 = fast_exp2(SVV[BASE + 0] - m_i), e1 = fast_exp2(SVV[BASE + 1] - m_i); \
            float e2 = fast_exp2(SVV[BASE + 2] - m_i), e3 = fast_exp2(SVV[BASE + 3] - m_i); \
            float e4 = fast_exp2(SVV[BASE + 4] - m_i), e5 = fast_exp2(SVV[BASE + 5] - m_i); \
            float e6 = fast_exp2(SVV[BASE + 6] - m_i), e7 = fast_exp2(SVV[BASE + 7] - m_i); \
            unsigned int Aw = pack_bf16(e0, e1), Bw = pack_bf16(e2, e3); \
            unsigned int Cw = pack_bf16(e4, e5), Dw = pack_bf16(e6, e7); \
            xchg(Aw, Cw, hl); xchg(Bw, Dw, hl); \
            PF = frag4(Aw, Bw, Cw, Dw); }
        PGROUP(sv[0], 0, pf0)
        PGROUP(sv[0], 8, pf1)
        PGROUP(sv[1], 0, pf2)
        PGROUP(sv[1], 8, pf3)
        #undef PGROUP

        if (t < 31) {     // K(t+1) -> other buffer; overlaps PV (no barrier)
            *(bf16x8*)&Ks[nxt][SW64(kr, kc)] = nka;
            *(bf16x8*)&Ks[nxt][SW64(kr + 32, kc)] = nkb;
        }

        // ---- O^T += V^T · P^T; lsum += ones · P^T (row-sum on MFMA pipe)
        #pragma unroll
        for (int js = 0; js < 4; js++) {
            bf16x8 av0 = *(const bf16x8*)&VTs[cur][SW64(l31, js * 16 + h8)];
            bf16x8 av1 = *(const bf16x8*)&VTs[cur][SW64(32 + l31, js * 16 + h8)];
            bf16x8 pb = (js == 0) ? pf0 : (js == 1) ? pf1 : (js == 2) ? pf2 : pf3;
            o_acc[0] = __builtin_amdgcn_mfma_f32_32x32x16_bf16(av0, pb, o_acc[0], 0, 0, 0);
            o_acc[1] = __builtin_amdgcn_mfma_f32_32x32x16_bf16(av1, pb, o_acc[1], 0, 0, 0);
            lsum = __builtin_amdgcn_mfma_f32_32x32x16_bf16(onesf, pb, lsum, 0, 0, 0);
        }

        if (t < 31) {     // V(t+1) transpose store -> other buffer
            #pragma unroll
            for (int j = 0; j < 8; j++)
                *(unsigned int*)&VTs[nxt][SW64(vc + j, vr2)] = pack2(nva[j], nvb[j]);
        }
    }

    // ---- epilogue: l = lsum[0] (row0 @ hl=0) + partner; O^T lane holds q=l31
    float lv = lsum[0];
    lv += __shfl_xor(lv, 32);
    float inv = 1.0f / lv;
    const int orow = q0 + wave * 32 + l31;
    #pragma unroll
    for (int dt = 0; dt < 2; dt++)
        #pragma unroll
        for (int g = 0; g < 4; g++) {
            bf16x4 ov;
            #pragma unroll
            for (int e = 0; e < 4; e++) ov[e] = (__bf16)(o_acc[dt][g * 4 + e] * inv);
            *(bf16x4*)&Og[base + orow * 1024 + dt * 32 + g * 8 + hl * 4] = ov;
        }
}

// ---------------------------------------------------------------------------
extern "C" void kernel_launch(void* const* d_in, const int* in_sizes, int n_in,
                              void* d_out, int out_size, void* d_ws, size_t ws_size,
                              hipStream_t stream)
{
    int* flag = (int*)d_ws;
    __bf16* cv = (__bf16*)((char*)d_ws + 256);

    // Region map (elem offsets into cv):
    //   0        z-bf16 [8192,1024]; reused as Ow after gemm_qkv consumes it
    //   8388608  wq^T/wk^T/wv^T [64,1024] x3      (gemm_qkv W1T)
    //   8585216  fcq_w^T/fck_w^T/fcv_w^T [1024,64] x3 (gemm_qkv W2T)
    //   8781824  fco_w^T [1024,1024]               (proj3 BT)
    //   9830400  biases fcq_b|fck_b|fcv_b|fco_b (4x1024, consecutive)
    //   12582912 Qw, +8388608 Kw, +16777216 Vw
    const int Z = 0, WQT = 8388608, FCWT = 8585216, FCOWT = 8781824, BIAS = 9830400;
    __bf16* Qw = cv + 12582912;
    __bf16* Kw = Qw + 8388608;
    __bf16* Vw = Kw + 8388608;
    __bf16* Ow = cv + Z;        // z-bf16 region, dead after gemm_qkv

    detect_dtype<<<1, 256, 0, stream>>>((const unsigned short*)d_in[0], flag);

    MegaArgs ma;
    ma.z = d_in[0];
    ma.bias[0] = d_in[5]; ma.bias[1] = d_in[7]; ma.bias[2] = d_in[9]; ma.bias[3] = d_in[11];
    ma.w[0] = d_in[1]; ma.w[1] = d_in[2]; ma.w[2] = d_in[3];          // wq wk wv [1024,64]
    ma.w[3] = d_in[4]; ma.w[4] = d_in[6]; ma.w[5] = d_in[8];          // fc*_w [64,1024]
    ma.w[6] = d_in[10];                                               // fco_w [1024,1024]
    mega_convert<<<dim3(1378, 1), 256, 0, stream>>>(ma, cv, flag);

    const float QSC = 0.125f * 1.44269504088896f;  // fold 1/sqrt(dk) * log2(e) into Q
    // proj1+proj2 fused: Q/K/V[8192,1024] = (z @ w*) @ fc*_w + b
    gemm_qkv<<<dim3(128, 1, 3), 256, 0, stream>>>(
        cv + Z, cv + WQT, cv + FCWT, cv + BIAS,
        Qw, Kw, Vw, QSC);

    attn_kernel<<<dim3(64, 16), 256, 0, stream>>>(Qw, Kw, Vw, Ow);

    // proj3: out[8192,1024] = Ow @ fco_w + b
    gemm128<<<dim3(64, 8, 1), 256, 0, stream>>>(
        Ow, cv + FCOWT, cv + BIAS + 3072,
        d_out, 8192, 1024, 1024, flag, 1.0f);
}

// Round 10
// 263.905 us; speedup vs baseline: 1.0404x; 1.0404x over previous
//
#include <hip/hip_runtime.h>

// multi_SelfAttention on MI355X (gfx950). Inputs fp32 (runtime-detected);
// bf16 MFMA compute; output dtype per flag.
// r17: r15 configuration (best measured: attn 104us VGPR64/occ31.7, separate
// gemm64+gemm128) with detect_dtype FUSED into mega_convert: every block
// recomputes the dtype flag locally (deterministic 16K-word scan, L2-hot,
// shared-atomic reduce); block 0 publishes it for proj3. One launch boundary
// (~10-15us) removed. r16 lessons: 32x32-MFMA l-sum costs 16 VGPR for 1
// scalar -> occupancy cliff (reverted); gemm_qkv phase-2 serialization eats
// the fusion gain (reverted).
// Launches: mega_convert -> gemm64 -> gemm128(proj2) -> attn -> gemm128(proj3).

typedef __bf16 bf16x8 __attribute__((ext_vector_type(8)));
typedef __bf16 bf16x4 __attribute__((ext_vector_type(4)));
typedef __bf16 bf16x2 __attribute__((ext_vector_type(2)));
typedef float floatx4 __attribute__((ext_vector_type(4)));
typedef float floatx16 __attribute__((ext_vector_type(16)));
typedef unsigned int uintx4 __attribute__((ext_vector_type(4)));
typedef unsigned int uintx2 __attribute__((ext_vector_type(2)));

// 64-stride tile swizzle: 16B-chunk XOR; bank-uniform for row-major b128
// reads at fixed col, b128 row-staging writes, and b32 transpose stores.
#define SW64(row, col) (((row) << 6) | (((((col) >> 3) ^ ((row) & 7) ^ (((row) >> 3) & 7)) << 3) | ((col) & 7)))

#if __has_builtin(__builtin_amdgcn_exp2f)
__device__ __forceinline__ float fast_exp2(float x) { return __builtin_amdgcn_exp2f(x); }
#else
__device__ __forceinline__ float fast_exp2(float x) { return exp2f(x); }
#endif

__device__ __forceinline__ unsigned int pack_bf16(float lo, float hi) {
    bf16x2 w; w[0] = (__bf16)lo; w[1] = (__bf16)hi;
    return __builtin_bit_cast(unsigned int, w);
}
__device__ __forceinline__ unsigned int pack2(__bf16 lo, __bf16 hi) {
    bf16x2 w; w[0] = lo; w[1] = hi;
    return __builtin_bit_cast(unsigned int, w);
}
// Cross-half exchange (lanes 0-31 <-> 32-63), verified builtin w/ shfl fallback.
#if __has_builtin(__builtin_amdgcn_permlane32_swap)
__device__ __forceinline__ void xchg(unsigned int& X, unsigned int& Y, int) {
    uintx2 r = __builtin_amdgcn_permlane32_swap(X, Y, false, false);
    X = r[0]; Y = r[1];
}
#else
__device__ __forceinline__ void xchg(unsigned int& X, unsigned int& Y, int hl) {
    unsigned int sX = (unsigned int)__shfl_xor((int)X, 32);
    unsigned int sY = (unsigned int)__shfl_xor((int)Y, 32);
    unsigned int lo = hl ? sY : X;
    unsigned int hi = hl ? Y : sX;
    X = lo; Y = hi;
}
#endif
__device__ __forceinline__ bf16x8 frag4(unsigned int a, unsigned int b, unsigned int c, unsigned int d) {
    uintx4 u; u[0] = a; u[1] = b; u[2] = c; u[3] = d;
    return __builtin_bit_cast(bf16x8, u);
}
// Async global->LDS DMA, 16 B/lane. LDS base must be wave-uniform; HW writes
// base + lane*16. Global addr is per-lane (pre-swizzle it for swizzled layouts).
__device__ __forceinline__ void async_b128(const __bf16* g, __bf16* l) {
    __builtin_amdgcn_global_load_lds(
        (const __attribute__((address_space(1))) unsigned int*)g,
        (__attribute__((address_space(3))) unsigned int*)l, 16, 0, 0);
}

__device__ __forceinline__ bf16x8 cvt8(const void* src, int f, long idx) {
    bf16x8 v;
    if (f) {
        const float* s = (const float*)src + idx;
        float4 f0 = *(const float4*)s;
        float4 f1 = *(const float4*)(s + 4);
        v[0] = (__bf16)f0.x; v[1] = (__bf16)f0.y; v[2] = (__bf16)f0.z; v[3] = (__bf16)f0.w;
        v[4] = (__bf16)f1.x; v[5] = (__bf16)f1.y; v[6] = (__bf16)f1.z; v[7] = (__bf16)f1.w;
    } else {
        v = *(const bf16x8*)((const __bf16*)src + idx);
    }
    return v;
}

// ---------------------------------------------------------------------------
// mega_convert: one kernel for the whole input-prep stage, INCLUDING dtype
// detection (fused; every block recomputes the flag deterministically from
// the same 16K words — L2-hot after the first block; block 0 publishes it
// for proj3).
//   blocks [0,1024):   z [8192,1024] convert/copy -> cv+0 (32 elems/thread)
//   blocks [1024,1026): 4 biases (consecutive dst at cv+9830400)
//   blocks [1026,1378): 64x64 transpose-convert tiles for 7 weight matrices:
//     t<48:  wq/wk/wv [1024,64] -> ^T [64,1024]   at cv+8388608 + m*65536
//     t<96:  fc*_w    [64,1024] -> ^T [1024,64]   at cv+8585216 + m*65536
//     else:  fco_w  [1024,1024] -> ^T [1024,1024] at cv+8781824
// ---------------------------------------------------------------------------
struct MegaArgs { const void* z; const void* bias[4]; const void* w[7]; };

__global__ __launch_bounds__(256) void mega_convert(MegaArgs a, __bf16* __restrict__ cv,
                                                    int* __restrict__ flag) {
    const unsigned int blk = blockIdx.x;
    const int tid = threadIdx.x;

    // ---- fused dtype detection (identical function to the old detect_dtype)
    __shared__ int cnt;
    if (tid == 0) cnt = 0;
    __syncthreads();
    {
        const unsigned short* zz = (const unsigned short*)a.z;
        int local = 0;
        for (int i = tid; i < 16384; i += 256) {
            unsigned int u = (unsigned int)zz[i] << 16;
            float x = __uint_as_float(u);
            float ax = fabsf(x);
            if (!(ax <= 1024.0f) || (x != 0.0f && ax < 1e-20f)) local++;
        }
        atomicAdd(&cnt, local);
    }
    __syncthreads();
    const int f = (cnt > 1310) ? 1 : 0;
    if (blk == 0 && tid == 0) *flag = f;   // for proj3's out-dtype switch

    if (blk < 1024) {           // z: 8388608 elems, 8192/block
        const long base = (long)blk * 8192 + tid * 8;
        #pragma unroll
        for (int p = 0; p < 4; p++) {
            const long i = base + p * 2048;
            *(bf16x8*)&cv[i] = cvt8(a.z, f, i);
        }
        return;
    }
    if (blk < 1026) {           // biases: 4 x 1024, consecutive dst
        const int idx = (((int)blk - 1024) * 256 + tid) * 8;
        const int b = idx >> 10, o = idx & 1023;
        *(bf16x8*)&cv[9830400 + b * 1024 + o] = cvt8(a.bias[b], f, o);
        return;
    }
    // ---- transpose-convert tiles
    const int t = blk - 1026;
    int bx, by, R, C;
    const void* src;
    __bf16* dst;
    if (t < 48) {
        const int m = t >> 4; by = t & 15; bx = 0; R = 1024; C = 64;
        src = a.w[m]; dst = cv + 8388608 + m * 65536;
    } else if (t < 96) {
        const int m = (t - 48) >> 4; bx = (t - 48) & 15; by = 0; R = 64; C = 1024;
        src = a.w[3 + m]; dst = cv + 8585216 + m * 65536;
    } else {
        const int u = t - 96; bx = u & 15; by = u >> 4; R = 1024; C = 1024;
        src = a.w[6]; dst = cv + 8781824;
    }
    __shared__ __bf16 tl[64][72];
    const int r0 = by * 64, c0 = bx * 64;
    const int rr = tid >> 3, c8 = (tid & 7) << 3;
    #pragma unroll
    for (int p = 0; p < 2; p++) {
        bf16x8 v = cvt8(src, f, (long)(r0 + p * 32 + rr) * C + c0 + c8);
        #pragma unroll
        for (int j = 0; j < 8; j++) tl[c8 + j][p * 32 + rr] = v[j];
    }
    __syncthreads();
    #pragma unroll
    for (int p = 0; p < 2; p++) {
        bf16x8 v;
        #pragma unroll
        for (int j = 0; j < 8; j++) v[j] = tl[p * 32 + rr][c8 + j];
        *(bf16x8*)&dst[(long)(c0 + p * 32 + rr) * R + r0 + c8] = v;
    }
}

// ---------------------------------------------------------------------------
// gemm64 (proj1): C[M,64] = A[M,K] @ BT[64,K]^T, bf16, no bias.
// 64x64 tile, BK=64, 4 waves (16 rows each). Both operands via global_load_lds
// with SW64-pre-swizzled source addresses (zero staging VALU, conflict-free).
// Grid (128,1,3) = 384 blocks: parallelism > fused-A reuse (r14 lesson).
// ---------------------------------------------------------------------------
__global__ __launch_bounds__(256, 2) void gemm64(
    const __bf16* __restrict__ A,
    const __bf16* __restrict__ BT0, const __bf16* __restrict__ BT1, const __bf16* __restrict__ BT2,
    __bf16* __restrict__ C0, __bf16* __restrict__ C1, __bf16* __restrict__ C2,
    int K)
{
    const int zsel = blockIdx.z;
    const __bf16* BT = (zsel == 0) ? BT0 : (zsel == 1) ? BT1 : BT2;
    __bf16* C = (zsel == 0) ? C0 : (zsel == 1) ? C1 : C2;
    const int m0 = blockIdx.x * 64;
    const int tid = threadIdx.x;
    const int wave = tid >> 6, ln = tid & 63;
    const int l15 = tid & 15, quad = (tid >> 4) & 3;

    __shared__ __bf16 As[64 * 64];   // SW64 [m][k], 8 KB
    __shared__ __bf16 Bs[64 * 64];   // SW64 [n][k], 8 KB

    const int r_off = ln >> 3, j_off = ln & 7;
    floatx4 acc[4] = {};

    for (int k0 = 0; k0 < K; k0 += 64) {
        __syncthreads();
        #pragma unroll
        for (int it = 0; it < 2; it++) {
            const int seg = wave * 2 + it;
            const int row = seg * 8 + r_off;
            const int c = j_off ^ (row & 7) ^ ((row >> 3) & 7);
            async_b128(&A[(long)(m0 + row) * K + k0 + c * 8], &As[seg * 512]);
            async_b128(&BT[(long)row * K + k0 + c * 8], &Bs[seg * 512]);
        }
        __syncthreads();
        #pragma unroll
        for (int ks = 0; ks < 2; ks++) {
            bf16x8 av = *(const bf16x8*)&As[SW64(wave * 16 + l15, ks * 32 + quad * 8)];
            #pragma unroll
            for (int nt = 0; nt < 4; nt++) {
                bf16x8 bv = *(const bf16x8*)&Bs[SW64(nt * 16 + l15, ks * 32 + quad * 8)];
                acc[nt] = __builtin_amdgcn_mfma_f32_16x16x32_bf16(av, bv, acc[nt], 0, 0, 0);
            }
        }
    }
    #pragma unroll
    for (int nt = 0; nt < 4; nt++) {
        const int col = nt * 16 + l15;
        #pragma unroll
        for (int r = 0; r < 4; r++)
            C[(long)(m0 + wave * 16 + quad * 4 + r) * 64 + col] = (__bf16)acc[nt][r];
    }
}

// ---------------------------------------------------------------------------
// gemm128: C[M,N] = (A @ BT^T + bias) * os. A[M,K], BT[N,K] both row-major.
// 128x128 tile, BK=64, 2x2 waves. Both tiles via global_load_lds w=16 with
// SW64-pre-swizzled source (zero staging VALU, conflict-free frag reads).
// ---------------------------------------------------------------------------
__global__ __launch_bounds__(256, 2) void gemm128(
    const __bf16* __restrict__ A0, const __bf16* __restrict__ A1, const __bf16* __restrict__ A2,
    const __bf16* __restrict__ BT0, const __bf16* __restrict__ BT1, const __bf16* __restrict__ BT2,
    const __bf16* __restrict__ bias0, const __bf16* __restrict__ bias1, const __bf16* __restrict__ bias2,
    void* __restrict__ C0, void* __restrict__ C1, void* __restrict__ C2,
    int M, int N, int K, const int* flagp,
    float os0, float os1, float os2)
{
    const int zsel = blockIdx.z;
    const __bf16* A = (zsel == 0) ? A0 : (zsel == 1) ? A1 : A2;
    const __bf16* BT = (zsel == 0) ? BT0 : (zsel == 1) ? BT1 : BT2;
    const __bf16* bias = (zsel == 0) ? bias0 : (zsel == 1) ? bias1 : bias2;
    void* C = (zsel == 0) ? C0 : (zsel == 1) ? C1 : C2;
    const float oscale = (zsel == 0) ? os0 : (zsel == 1) ? os1 : os2;
    const int out_fp32 = flagp ? *flagp : 0;

    const int m0 = blockIdx.x * 128;
    const int n0 = blockIdx.y * 128;
    const int tid = threadIdx.x;
    const int wave = tid >> 6, ln = tid & 63;
    const int wr = wave >> 1, wc = wave & 1;    // 2x2 wave grid
    const int l15 = tid & 15, quad = (tid >> 4) & 3;

    __shared__ __bf16 As[128 * 64];   // SW64 layout [m][k], 16 KB
    __shared__ __bf16 Bs[128 * 64];   // SW64 layout [n][k], 16 KB

    const int r_off = ln >> 3, j_off = ln & 7;

    floatx4 acc[4][4] = {};

    for (int k0 = 0; k0 < K; k0 += 64) {
        __syncthreads();
        #pragma unroll
        for (int it = 0; it < 4; it++) {
            const int seg = wave * 4 + it;
            const int row = seg * 8 + r_off;
            const int c = j_off ^ (row & 7) ^ ((row >> 3) & 7);
            async_b128(&A[(long)(m0 + row) * K + k0 + c * 8], &As[seg * 512]);
            async_b128(&BT[(long)(n0 + row) * K + k0 + c * 8], &Bs[seg * 512]);
        }
        __syncthreads();
        #pragma unroll
        for (int ks = 0; ks < 2; ks++) {
            bf16x8 a[4], b[4];
            #pragma unroll
            for (int rt = 0; rt < 4; rt++)
                a[rt] = *(const bf16x8*)&As[SW64(wr * 64 + rt * 16 + l15, ks * 32 + quad * 8)];
            #pragma unroll
            for (int nt = 0; nt < 4; nt++)
                b[nt] = *(const bf16x8*)&Bs[SW64(wc * 64 + nt * 16 + l15, ks * 32 + quad * 8)];
            #pragma unroll
            for (int rt = 0; rt < 4; rt++)
                #pragma unroll
                for (int nt = 0; nt < 4; nt++)
                    acc[rt][nt] = __builtin_amdgcn_mfma_f32_16x16x32_bf16(a[rt], b[nt], acc[rt][nt], 0, 0, 0);
        }
    }
    #pragma unroll
    for (int rt = 0; rt < 4; rt++) {
        const int row = m0 + wr * 64 + rt * 16 + quad * 4;
        #pragma unroll
        for (int nt = 0; nt < 4; nt++) {
            const int col = n0 + wc * 64 + nt * 16 + l15;
            float bv = (float)bias[col];
            #pragma unroll
            for (int r = 0; r < 4; r++) {
                float val = (acc[rt][nt][r] + bv) * oscale;
                if (out_fp32) ((float*)C)[(long)(row + r) * N + col] = val;
                else ((__bf16*)C)[(long)(row + r) * N + col] = (__bf16)val;
            }
        }
    }
}

// ---------------------------------------------------------------------------
// Flash attention (32x32 S^T / O^T, in-register P, single-barrier loop).
// r14/r15 version: exp2->pack->xchg fused per 8-group, VALU row-sum
// (VGPR 64, 3 blocks/CU, 104 us measured). r16's MFMA l-sum reverted
// (16-reg accumulator -> occupancy cliff).
// ---------------------------------------------------------------------------
__global__ __launch_bounds__(256, 3) void attn_kernel(
    const __bf16* __restrict__ Qg, const __bf16* __restrict__ Kg,
    const __bf16* __restrict__ Vg, __bf16* __restrict__ Og)
{
    const int bh = blockIdx.x;
    const int b = bh >> 4, h = bh & 15;
    const int q0 = blockIdx.y * 128;
    const int base = b * 2048 * 1024 + h * 64;
    const int tid = threadIdx.x;
    const int wave = tid >> 6, ln = tid & 63;
    const int l31 = ln & 31, hl = ln >> 5;    // lane-in-32, lane half
    const int h8 = hl * 8;

    __shared__ __bf16 Ks[2][64 * 64];     // 16 KB, double buffer, SW64 [j][k]
    __shared__ __bf16 VTs[2][64 * 64];    // 16 KB, double buffer, SW64 [d][j]

    // Q fragments (B-operand of S^T): lane n=q=l31, k = ks*16 + h8 + e
    bf16x8 qf[4];
    #pragma unroll
    for (int ks = 0; ks < 4; ks++)
        qf[ks] = *(const bf16x8*)&Qg[base + (q0 + wave * 32 + l31) * 1024 + ks * 16 + h8];

    const int kr = tid >> 3, kc = (tid & 7) << 3;   // K staging: rows kr, kr+32
    const int vr2 = (tid >> 3) * 2, vc = (tid & 7) << 3;  // V staging: row pair

    {   // tile 0 (published by the t=0 barrier)
        bf16x8 ka = *(const bf16x8*)&Kg[base + kr * 1024 + kc];
        bf16x8 kb = *(const bf16x8*)&Kg[base + (kr + 32) * 1024 + kc];
        bf16x8 va = *(const bf16x8*)&Vg[base + vr2 * 1024 + vc];
        bf16x8 vb = *(const bf16x8*)&Vg[base + (vr2 + 1) * 1024 + vc];
        *(bf16x8*)&Ks[0][SW64(kr, kc)] = ka;
        *(bf16x8*)&Ks[0][SW64(kr + 32, kc)] = kb;
        #pragma unroll
        for (int j = 0; j < 8; j++)
            *(unsigned int*)&VTs[0][SW64(vc + j, vr2)] = pack2(va[j], vb[j]);
    }

    floatx16 o_acc[2] = {};
    float m_i = -1e30f, l_i = 0.0f;

    for (int t = 0; t < 32; t++) {
        const int cur = t & 1, nxt = cur ^ 1;
        bf16x8 nka, nkb, nva, nvb;          // K/V(t+1) register prefetch
        if (t < 31) {
            const int kvn = (t + 1) * 64;
            nka = *(const bf16x8*)&Kg[base + (kvn + kr) * 1024 + kc];
            nkb = *(const bf16x8*)&Kg[base + (kvn + kr + 32) * 1024 + kc];
            nva = *(const bf16x8*)&Vg[base + (kvn + vr2) * 1024 + vc];
            nvb = *(const bf16x8*)&Vg[base + (kvn + vr2 + 1) * 1024 + vc];
        }
        __syncthreads();  // writes(t-1) -> nxt_{t-1}=cur visible; reads(t-1) drained

        // ---- S^T = K · Q^T: lane q=l31; j = (r&3)+8*(r>>2)+4*hl (+32 for s1)
        floatx16 sv[2] = {};
        #pragma unroll
        for (int ks = 0; ks < 4; ks++) {
            bf16x8 a0 = *(const bf16x8*)&Ks[cur][SW64(l31, ks * 16 + h8)];
            bf16x8 a1 = *(const bf16x8*)&Ks[cur][SW64(32 + l31, ks * 16 + h8)];
            sv[0] = __builtin_amdgcn_mfma_f32_32x32x16_bf16(a0, qf[ks], sv[0], 0, 0, 0);
            sv[1] = __builtin_amdgcn_mfma_f32_32x32x16_bf16(a1, qf[ks], sv[1], 0, 0, 0);
        }

        // ---- softmax max for q=l31 over 64 j (left-nested for v_max3 fusion)
        float m8[8];
        #pragma unroll
        for (int r = 0; r < 8; r++)
            m8[r] = fmaxf(fmaxf(fmaxf(sv[0][r], sv[0][r + 8]), sv[1][r]), sv[1][r + 8]);
        float ma = fmaxf(fmaxf(m8[0], m8[1]), m8[2]);
        float mb = fmaxf(fmaxf(m8[3], m8[4]), m8[5]);
        float mc = fmaxf(fmaxf(m8[6], m8[7]), ma);
        float mx = fmaxf(mb, mc);
        mx = fmaxf(mx, __shfl_xor(mx, 32));

        if (__any(mx > m_i + 8.0f)) {       // defer-max: rescale only on big jumps
            float m_new = fmaxf(m_i, mx);
            float alpha = fast_exp2(m_i - m_new);
            m_i = m_new;
            l_i *= alpha;
            #pragma unroll
            for (int dt = 0; dt < 2; dt++)
                #pragma unroll
                for (int r = 0; r < 16; r++) o_acc[dt][r] *= alpha;
        }

        // ---- P: exp2 -> bf16 pack -> cross-half exchange, fused per 8-group
        // (fp32 values die within the group; only 4 packed words live on)
        float rsA = 0.f, rsB = 0.f, rsC = 0.f, rsD = 0.f;
        bf16x8 pf0, pf1, pf2, pf3;
        #define PGROUP(SVV, BASE, PF) { \
            float e0 = fast_exp2(SVV[BASE + 0] - m_i), e1 = fast_exp2(SVV[BASE + 1] - m_i); \
            float e2 = fast_exp2(SVV[BASE + 2] - m_i), e3 = fast_exp2(SVV[BASE + 3] - m_i); \
            float e4 = fast_exp2(SVV[BASE + 4] - m_i), e5 = fast_exp2(SVV[BASE + 5] - m_i); \
            float e6 = fast_exp2(SVV[BASE + 6] - m_i), e7 = fast_exp2(SVV[BASE + 7] - m_i); \
            rsA += e0 + e4; rsB += e1 + e5; rsC += e2 + e6; rsD += e3 + e7; \
            unsigned int Aw = pack_bf16(e0, e1), Bw = pack_bf16(e2, e3); \
            unsigned int Cw = pack_bf16(e4, e5), Dw = pack_bf16(e6, e7); \
            xchg(Aw, Cw, hl); xchg(Bw, Dw, hl); \
            PF = frag4(Aw, Bw, Cw, Dw); }
        PGROUP(sv[0], 0, pf0)
        PGROUP(sv[0], 8, pf1)
        PGROUP(sv[1], 0, pf2)
        PGROUP(sv[1], 8, pf3)
        #undef PGROUP
        float rs = (rsA + rsB) + (rsC + rsD);
        rs += __shfl_xor(rs, 32);
        l_i += rs;

        if (t < 31) {     // K(t+1) -> other buffer; overlaps PV (no barrier)
            *(bf16x8*)&Ks[nxt][SW64(kr, kc)] = nka;
            *(bf16x8*)&Ks[nxt][SW64(kr + 32, kc)] = nkb;
        }

        // ---- O^T += V^T · P^T  (A = VTs rows b128, B = P-frags in regs)
        #pragma unroll
        for (int js = 0; js < 4; js++) {
            bf16x8 av0 = *(const bf16x8*)&VTs[cur][SW64(l31, js * 16 + h8)];
            bf16x8 av1 = *(const bf16x8*)&VTs[cur][SW64(32 + l31, js * 16 + h8)];
            bf16x8 pb = (js == 0) ? pf0 : (js == 1) ? pf1 : (js == 2) ? pf2 : pf3;
            o_acc[0] = __builtin_amdgcn_mfma_f32_32x32x16_bf16(av0, pb, o_acc[0], 0, 0, 0);
            o_acc[1] = __builtin_amdgcn_mfma_f32_32x32x16_bf16(av1, pb, o_acc[1], 0, 0, 0);
        }

        if (t < 31) {     // V(t+1) transpose store -> other buffer
            #pragma unroll
            for (int j = 0; j < 8; j++)
                *(unsigned int*)&VTs[nxt][SW64(vc + j, vr2)] = pack2(nva[j], nvb[j]);
        }
    }

    // ---- epilogue: O^T lane holds q=l31, d = dt*32 + 8g + 4*hl + e
    float inv = 1.0f / l_i;
    const int orow = q0 + wave * 32 + l31;
    #pragma unroll
    for (int dt = 0; dt < 2; dt++)
        #pragma unroll
        for (int g = 0; g < 4; g++) {
            bf16x4 ov;
            #pragma unroll
            for (int e = 0; e < 4; e++) ov[e] = (__bf16)(o_acc[dt][g * 4 + e] * inv);
            *(bf16x4*)&Og[base + orow * 1024 + dt * 32 + g * 8 + hl * 4] = ov;
        }
}

// ---------------------------------------------------------------------------
extern "C" void kernel_launch(void* const* d_in, const int* in_sizes, int n_in,
                              void* d_out, int out_size, void* d_ws, size_t ws_size,
                              hipStream_t stream)
{
    int* flag = (int*)d_ws;
    __bf16* cv = (__bf16*)((char*)d_ws + 256);

    // Region map (elem offsets into cv):
    //   0        z-bf16 [8192,1024]; reused as Ow after proj1 consumes it
    //   8388608  wq^T/wk^T/wv^T [64,1024] x3      (proj1 BT)
    //   8585216  fcq_w^T/fck_w^T/fcv_w^T [1024,64] x3 (proj2 BT)
    //   8781824  fco_w^T [1024,1024]               (proj3 BT)
    //   9830400  biases fcq_b|fck_b|fcv_b|fco_b (4x1024, consecutive)
    //   10485760 zb [8192,64] x3 (proj1 out)
    //   12582912 Qw, +8388608 Kw, +16777216 Vw
    const int Z = 0, WQT = 8388608, FCWT = 8585216, FCOWT = 8781824, BIAS = 9830400;
    __bf16* zb = cv + 10485760;
    __bf16* Qw = cv + 12582912;
    __bf16* Kw = Qw + 8388608;
    __bf16* Vw = Kw + 8388608;
    __bf16* Ow = cv + Z;        // z-bf16 region, dead after proj1

    MegaArgs ma;
    ma.z = d_in[0];
    ma.bias[0] = d_in[5]; ma.bias[1] = d_in[7]; ma.bias[2] = d_in[9]; ma.bias[3] = d_in[11];
    ma.w[0] = d_in[1]; ma.w[1] = d_in[2]; ma.w[2] = d_in[3];          // wq wk wv [1024,64]
    ma.w[3] = d_in[4]; ma.w[4] = d_in[6]; ma.w[5] = d_in[8];          // fc*_w [64,1024]
    ma.w[6] = d_in[10];                                               // fco_w [1024,1024]
    mega_convert<<<dim3(1378, 1), 256, 0, stream>>>(ma, cv, flag);

    // proj1: zb[8192,64]x3 = z @ w{q,k,v}   (BT = w^T [64,1024])
    gemm64<<<dim3(128, 1, 3), 256, 0, stream>>>(
        cv + Z, cv + WQT, cv + WQT + 65536, cv + WQT + 131072,
        zb, zb + 524288, zb + 1048576, 1024);

    const float QSC = 0.125f * 1.44269504088896f;  // fold 1/sqrt(dk) * log2(e) into Q
    // proj2: Q/K/V[8192,1024] = zb @ fc*_w + b
    gemm128<<<dim3(64, 8, 3), 256, 0, stream>>>(
        zb, zb + 524288, zb + 1048576,
        cv + FCWT, cv + FCWT + 65536, cv + FCWT + 131072,
        cv + BIAS, cv + BIAS + 1024, cv + BIAS + 2048,
        Qw, Kw, Vw, 8192, 1024, 64, nullptr,
        QSC, 1.0f, 1.0f);

    attn_kernel<<<dim3(64, 16), 256, 0, stream>>>(Qw, Kw, Vw, Ow);

    // proj3: out[8192,1024] = Ow @ fco_w + b
    gemm128<<<dim3(64, 8, 1), 256, 0, stream>>>(
        Ow, Ow, Ow, cv + FCOWT, cv + FCOWT, cv + FCOWT,
        cv + BIAS + 3072, cv + BIAS + 3072, cv + BIAS + 3072,
        d_out, d_out, d_out, 8192, 1024, 1024, flag,
        1.0f, 1.0f, 1.0f);
}